// Round 1
// baseline (306.929 us; speedup 1.0000x reference)
//
#include <hip/hip_runtime.h>

#define F 4096          // feature dim (S_DIM == HID == A_DIM)
#define NE 44
#define NN 14
#define YPART 57344     // 14*4096, one partial Y buffer
#define H1SZ 180224     // 44*4096

// deterministic edge list from reference _edge_list()
__device__ constexpr int SRC[NE] = {
    0,1,2,3,4,5,6,7,8,9,10,11,12,13,          // fwd ring
    1,2,3,4,5,6,7,8,9,10,11,12,13,0,          // rev ring
    0,1,2,3,4,5,6,7,8,9,10,11,12,13,          // skip-2 ring
    0,7};
__device__ constexpr int DST[NE] = {
    1,2,3,4,5,6,7,8,9,10,11,12,13,0,
    0,1,2,3,4,5,6,7,8,9,10,11,12,13,
    2,3,4,5,6,7,8,9,10,11,12,13,0,1,
    7,0};
// deg: 3 everywhere except nodes 0 and 7 (4)
__device__ constexpr float INVDEG[NN] = {
    0.25f, 1.f/3.f, 1.f/3.f, 1.f/3.f, 1.f/3.f, 1.f/3.f, 1.f/3.f,
    0.25f, 1.f/3.f, 1.f/3.f, 1.f/3.f, 1.f/3.f, 1.f/3.f, 1.f/3.f};

// ---------------- prep: A = node2(edge_features) -------------------------
// layer-1 input: edge features are x directly
__global__ __launch_bounds__(256) void prep_x_k(const float* __restrict__ x,
                                                float* __restrict__ Aout) {
    int f = blockIdx.x * 256 + threadIdx.x;   // 16 blocks cover 4096
    float s[NN];
#pragma unroll
    for (int n = 0; n < NN; ++n) s[n] = 0.f;
#pragma unroll
    for (int e = 0; e < NE; ++e) s[DST[e]] += x[e * F + f];
    float node[NN];
#pragma unroll
    for (int n = 0; n < NN; ++n) node[n] = s[n] * INVDEG[n];
    float n2[NN];
#pragma unroll
    for (int n = 0; n < NN; ++n) n2[n] = 0.f;
#pragma unroll
    for (int e = 0; e < NE; ++e) n2[DST[e]] += node[SRC[e]];
#pragma unroll
    for (int m = 0; m < NN; ++m) Aout[m * F + f] = n2[m];
}

// inner layers: edge feat = leaky_relu(0.5*(Y[src]+Y[dst]) + b), Y = p0+p1
__device__ __forceinline__ void prep_col(const float* __restrict__ Yp,
                                         const float* __restrict__ b,
                                         float* __restrict__ Aout, int f) {
    float y[NN];
#pragma unroll
    for (int m = 0; m < NN; ++m) y[m] = Yp[m * F + f] + Yp[YPART + m * F + f];
    float bias = b[f];
    float s[NN];
#pragma unroll
    for (int n = 0; n < NN; ++n) s[n] = 0.f;
#pragma unroll
    for (int e = 0; e < NE; ++e) {
        float eh = 0.5f * (y[SRC[e]] + y[DST[e]]) + bias;
        eh = eh > 0.f ? eh : 0.01f * eh;      // leaky_relu(0.01)
        s[DST[e]] += eh;
    }
    float node[NN];
#pragma unroll
    for (int n = 0; n < NN; ++n) node[n] = s[n] * INVDEG[n];
    float n2[NN];
#pragma unroll
    for (int n = 0; n < NN; ++n) n2[n] = 0.f;
#pragma unroll
    for (int e = 0; e < NE; ++e) n2[DST[e]] += node[SRC[e]];
#pragma unroll
    for (int m = 0; m < NN; ++m) Aout[m * F + f] = n2[m];
}

// two preps (a-branch, v-branch) in one launch: 32 blocks
__global__ __launch_bounds__(256) void prep2_k(const float* __restrict__ Yp1,
                                               const float* __restrict__ b1,
                                               float* __restrict__ A1,
                                               const float* __restrict__ Yp2,
                                               const float* __restrict__ b2,
                                               float* __restrict__ A2) {
    int bx = blockIdx.x;
    if (bx < 16) {
        prep_col(Yp1, b1, A1, bx * 256 + threadIdx.x);
    } else {
        prep_col(Yp2, b2, A2, (bx - 16) * 256 + threadIdx.x);
    }
}

// ---------------- GEMM: Y[m][n] = sum_k A[m][k] * W[n][k] ----------------
// A: 14x4096 (L2 resident), W: 4096x4096 streamed from HBM.
// 512 blocks per half: nb (256) x kb (2). Block = 4 waves, wave owns 4 rows.
// Lane owns a float4 k-slice per pass; 8 passes cover the 2048-wide k chunk.
// Partial output per k-chunk written to Y[kb*YPART + ...] (no atomics).
__global__ __launch_bounds__(256) void gemm2_k(const float* __restrict__ A1,
                                               const float* __restrict__ W1,
                                               float* __restrict__ Y1,
                                               const float* __restrict__ A2,
                                               const float* __restrict__ W2,
                                               float* __restrict__ Y2) {
    int bx = blockIdx.x;
    const float* A = A1; const float* W = W1; float* Y = Y1;
    if (bx >= 512) { A = A2; W = W2; Y = Y2; bx -= 512; }
    const int kb = bx & 1;          // k chunk (2048 wide)
    const int nb = bx >> 1;         // 256 row-blocks of 16
    const int w  = threadIdx.x >> 6;
    const int l  = threadIdx.x & 63;
    const int r0 = nb * 16 + w * 4; // 4 W-rows for this wave
    const int k0 = kb * 2048;

    float acc[4][NN];
#pragma unroll
    for (int r = 0; r < 4; ++r)
#pragma unroll
        for (int m = 0; m < NN; ++m) acc[r][m] = 0.f;

    for (int p = 0; p < 8; ++p) {
        const int kq = k0 + (p * 64 + l) * 4;   // this lane's float4 start
        float4 a[NN];
#pragma unroll
        for (int m = 0; m < NN; ++m)
            a[m] = *(const float4*)(A + m * F + kq);
#pragma unroll
        for (int r = 0; r < 4; ++r) {
            float4 wv = *(const float4*)(W + (size_t)(r0 + r) * F + kq);
#pragma unroll
            for (int m = 0; m < NN; ++m)
                acc[r][m] += wv.x * a[m].x + wv.y * a[m].y +
                             wv.z * a[m].z + wv.w * a[m].w;
        }
    }
    // butterfly reduce each (row, m) over the 64 lanes
#pragma unroll
    for (int r = 0; r < 4; ++r) {
#pragma unroll
        for (int m = 0; m < NN; ++m) {
            float v = acc[r][m];
#pragma unroll
            for (int off = 32; off > 0; off >>= 1) v += __shfl_xor(v, off);
            if (l == 0) Y[kb * YPART + m * F + (r0 + r)] = v;
        }
    }
}

// ---------------- final: h1 edge expansion + h2 tiny GEMM ----------------
__global__ __launch_bounds__(256) void final_k(const float* __restrict__ Ypa5,
                                               const float* __restrict__ ba5,
                                               const float* __restrict__ Av2,
                                               const float* __restrict__ Wv5,
                                               const float* __restrict__ bv5,
                                               float* __restrict__ out) {
    __shared__ float red[NN][257];
    if (blockIdx.x < 704) {
        int idx = blockIdx.x * 256 + threadIdx.x;  // 44*4096
        int e = idx >> 12, f = idx & 4095;
        int se = SRC[e], de = DST[e];
        float ys = Ypa5[se * F + f] + Ypa5[YPART + se * F + f];
        float yd = Ypa5[de * F + f] + Ypa5[YPART + de * F + f];
        out[idx] = 0.5f * (ys + yd) + ba5[f];
    } else {
        // y[n] = dot(Av2[n], Wv5); h2[e] = 0.5*(y[src]+y[dst]) + bv5
        int t = threadIdx.x;
        float acc[NN];
#pragma unroll
        for (int m = 0; m < NN; ++m) acc[m] = 0.f;
        for (int f = t; f < F; f += 256) {
            float wv = Wv5[f];
#pragma unroll
            for (int m = 0; m < NN; ++m) acc[m] += Av2[m * F + f] * wv;
        }
#pragma unroll
        for (int m = 0; m < NN; ++m) red[m][t] = acc[m];
        __syncthreads();
        for (int s = 128; s > 0; s >>= 1) {
            if (t < s) {
#pragma unroll
                for (int m = 0; m < NN; ++m) red[m][t] += red[m][t + s];
            }
            __syncthreads();
        }
        if (t < NE) {
            float ys = red[SRC[t]][0], yd = red[DST[t]][0];
            out[H1SZ + t] = 0.5f * (ys + yd) + bv5[0];
        }
    }
}

extern "C" void kernel_launch(void* const* d_in, const int* in_sizes, int n_in,
                              void* d_out, int out_size, void* d_ws, size_t ws_size,
                              hipStream_t stream) {
    const float* x   = (const float*)d_in[0];
    const float* Wa1 = (const float*)d_in[3];
    const float* ba1 = (const float*)d_in[4];
    const float* Wa2 = (const float*)d_in[5];
    const float* ba2 = (const float*)d_in[6];
    const float* Wa5 = (const float*)d_in[7];
    const float* ba5 = (const float*)d_in[8];
    const float* Wv1 = (const float*)d_in[9];
    const float* bv1 = (const float*)d_in[10];
    const float* Wv2 = (const float*)d_in[11];
    const float* bv2 = (const float*)d_in[12];
    const float* Wv5 = (const float*)d_in[13];
    const float* bv5 = (const float*)d_in[14];
    float* out = (float*)d_out;

    float* ws  = (float*)d_ws;
    float* Ax  = ws;                 // 57344
    float* Aa  = ws + 57344;         // 57344
    float* Av  = ws + 114688;        // 57344
    float* Ypa = ws + 172032;        // 2*57344
    float* Ypv = ws + 286720;        // 2*57344  (total 401408 floats = 1.6 MB)

    prep_x_k<<<16, 256, 0, stream>>>(x, Ax);
    gemm2_k <<<1024, 256, 0, stream>>>(Ax, Wa1, Ypa, Ax, Wv1, Ypv);
    prep2_k <<<32, 256, 0, stream>>>(Ypa, ba1, Aa, Ypv, bv1, Av);
    gemm2_k <<<1024, 256, 0, stream>>>(Aa, Wa2, Ypa, Av, Wv2, Ypv);
    prep2_k <<<32, 256, 0, stream>>>(Ypa, ba2, Aa, Ypv, bv2, Av);
    gemm2_k <<<512, 256, 0, stream>>>(Aa, Wa5, Ypa, Aa, Wa5, Ypa);
    final_k <<<705, 256, 0, stream>>>(Ypa, ba5, Av, Wv5, bv5, out);
}